// Round 2
// baseline (1066.916 us; speedup 1.0000x reference)
//
#include <hip/hip_runtime.h>

#define DEFAULT_SCORE -10000.0f

// One 64-lane wave per row: lane k owns column k.
// cond is wave-uniform -> the dist[] read is skipped for ~98.4% of rows.
// The harness decodes the whole d_out buffer as float32, so nidx_out is
// written as float-encoded integers ((float)idx, -1.0f). idx < 2^24 -> exact.
__global__ __launch_bounds__(256) void dgb_kernel(
    const float* __restrict__ dist,
    const int*   __restrict__ nidx,
    const float* __restrict__ score,
    float*       __restrict__ dist_out,
    float*       __restrict__ nidx_out,
    int V) {
  const int lane = threadIdx.x & 63;
  const int row  = blockIdx.x * (blockDim.x >> 6) + (threadIdx.x >> 6);
  if (row >= V) return;

  const size_t base = (size_t)row * 64 + lane;

  // Load my column's neighbour index (coalesced: 64 lanes x 4 B = 256 B).
  const int idx = nidx[base];

  // Gathered neighbour score; column 0 (self) is excluded from the max,
  // idx < 0 means "no neighbour" -> default.
  float ns = (lane == 0 || idx < 0) ? DEFAULT_SCORE : score[idx];

  // Butterfly max across all 64 lanes (lane 0 contributes DEFAULT_SCORE).
#pragma unroll
  for (int off = 1; off < 64; off <<= 1)
    ns = fmaxf(ns, __shfl_xor(ns, off, 64));

  // Self score: same address for all lanes in the wave -> broadcast load.
  const float self = score[row];
  const bool cond = (self - ns) < 0.0f;  // wave-uniform

  float d, ni;
  if (cond) {
    d  = 0.0f;
    ni = (lane == 0) ? (float)idx : -1.0f;
  } else {
    d  = dist[base];  // only ~1.6% of rows reach this load
    ni = (float)idx;
  }

  dist_out[base] = d;
  nidx_out[base] = ni;
}

extern "C" void kernel_launch(void* const* d_in, const int* in_sizes, int n_in,
                              void* d_out, int out_size, void* d_ws, size_t ws_size,
                              hipStream_t stream) {
  const float* dist  = (const float*)d_in[0];  // [V, 64] f32
  const int*   nidx  = (const int*)d_in[1];    // [V, 64] i32
  const float* score = (const float*)d_in[2];  // [V, 1]  f32

  const int V = in_sizes[2];  // score has V elements

  float* dist_out = (float*)d_out;                           // V*64 floats
  float* nidx_out = (float*)d_out + (size_t)V * 64;          // V*64 float-encoded ints

  const int rows_per_block = 256 / 64;  // 4 waves per block, 1 row per wave
  const int grid = (V + rows_per_block - 1) / rows_per_block;

  dgb_kernel<<<grid, 256, 0, stream>>>(dist, nidx, score, dist_out, nidx_out, V);
}

// Round 3
// 1005.457 us; speedup vs baseline: 1.0611x; 1.0611x over previous
//
#include <hip/hip_runtime.h>

#define DEFAULT_SCORE -10000.0f

// One 64-lane wave handles R=8 rows: lane k owns column k of each row.
// - 8 gathers in flight per wave (MLP) instead of 1.
// - All streaming traffic (nidx in, dist in, both outputs) is non-temporal so
//   the 4 MB score[] table stays resident in each XCD's 4 MB L2 for the gather.
// - Self score comes from lane 0's gather (nidx[v,0] == v by convention),
//   broadcast via shuffle: no separate score[row] load.
// - cond is wave-uniform -> dist[] read skipped for ~98.4% of rows.
// Harness decodes d_out as float32 -> nidx_out written as float-encoded ints.
constexpr int R = 8;

__global__ __launch_bounds__(256) void dgb_kernel(
    const float* __restrict__ dist,
    const int*   __restrict__ nidx,
    const float* __restrict__ score,
    float*       __restrict__ dist_out,
    float*       __restrict__ nidx_out,
    int V) {
  const int lane = threadIdx.x & 63;
  const int wave = blockIdx.x * (blockDim.x >> 6) + (threadIdx.x >> 6);
  const int row0 = wave * R;

  int idx[R];
  size_t base[R];
  // Issue all R row-index loads back-to-back (independent, non-temporal).
#pragma unroll
  for (int r = 0; r < R; ++r) {
    const int row = row0 + r;
    base[r] = (size_t)row * 64 + lane;
    idx[r] = (row < V) ? __builtin_nontemporal_load(&nidx[base[r]]) : -1;
  }

  // Issue all R gathers back-to-back; score[] is the only L2-cached stream.
  float g[R];
#pragma unroll
  for (int r = 0; r < R; ++r)
    g[r] = (idx[r] < 0) ? DEFAULT_SCORE : score[idx[r]];

  // Self score = lane 0's gather (nidx[v,0] == v); butterfly max over the
  // neighbour lanes (lane 0 contributes DEFAULT_SCORE). Interleaved for ILP.
  float self[R], ns[R];
#pragma unroll
  for (int r = 0; r < R; ++r) {
    self[r] = __shfl(g[r], 0, 64);
    ns[r] = (lane == 0) ? DEFAULT_SCORE : g[r];
  }
#pragma unroll
  for (int off = 1; off < 64; off <<= 1) {
#pragma unroll
    for (int r = 0; r < R; ++r)
      ns[r] = fmaxf(ns[r], __shfl_xor(ns[r], off, 64));
  }

#pragma unroll
  for (int r = 0; r < R; ++r) {
    const int row = row0 + r;
    if (row >= V) continue;
    const bool cond = self[r] < ns[r];  // wave-uniform
    float d, ni;
    if (cond) {
      d  = 0.0f;
      ni = (lane == 0) ? (float)idx[r] : -1.0f;
    } else {
      d  = __builtin_nontemporal_load(&dist[base[r]]);  // ~1.6% of rows
      ni = (float)idx[r];
    }
    __builtin_nontemporal_store(d,  &dist_out[base[r]]);
    __builtin_nontemporal_store(ni, &nidx_out[base[r]]);
  }
}

extern "C" void kernel_launch(void* const* d_in, const int* in_sizes, int n_in,
                              void* d_out, int out_size, void* d_ws, size_t ws_size,
                              hipStream_t stream) {
  const float* dist  = (const float*)d_in[0];  // [V, 64] f32
  const int*   nidx  = (const int*)d_in[1];    // [V, 64] i32
  const float* score = (const float*)d_in[2];  // [V, 1]  f32

  const int V = in_sizes[2];

  float* dist_out = (float*)d_out;                    // V*64 floats
  float* nidx_out = (float*)d_out + (size_t)V * 64;   // V*64 float-encoded ints

  const int rows_per_block = (256 / 64) * R;  // 4 waves x 8 rows = 32 rows/block
  const int grid = (V + rows_per_block - 1) / rows_per_block;

  dgb_kernel<<<grid, 256, 0, stream>>>(dist, nidx, score, dist_out, nidx_out, V);
}